// Round 8
// baseline (522.263 us; speedup 1.0000x reference)
//
#include <hip/hip_runtime.h>
#include <hip/hip_bf16.h>

#define N_ROWS 16384
#define DIN_K  256
#define DOUT_K 64
#define M_COLS 16384
#define LOG2E  1.4426950408889634f

typedef __attribute__((ext_vector_type(8))) short short8;
typedef __attribute__((ext_vector_type(4))) float f32x4;

#define MFMA16 __builtin_amdgcn_mfma_f32_16x16x32_bf16
#define EXP2F  __builtin_amdgcn_exp2f
#define LOG2F  __builtin_amdgcn_logf

__device__ inline unsigned short f32_bf16_rne(float x) {
    unsigned u = __builtin_bit_cast(unsigned, x);
    u += 0x7fffu + ((u >> 16) & 1u);
    return (unsigned short)(u >> 16);
}
__device__ inline float bf16_f32(unsigned short h) {
    unsigned u = ((unsigned)h) << 16;
    return __builtin_bit_cast(float, u);
}

// ---------------------------------------------------------------------------
// Kernel 1: before = (X @ W) * log2(e); split to bf16 hi/lo; per-row exp bound
// ---------------------------------------------------------------------------
__global__ __launch_bounds__(256) void k_before(
    const float* __restrict__ X, const float* __restrict__ W,
    float* __restrict__ off2,
    unsigned short* __restrict__ bh, unsigned short* __restrict__ bl)
{
    const int row  = blockIdx.x * 4 + (threadIdx.x >> 6);
    const int lane = threadIdx.x & 63;
    const float* xr = X + (size_t)row * DIN_K;
    float acc = 0.f;
    #pragma unroll 8
    for (int d = 0; d < DIN_K; ++d)
        acc = fmaf(xr[d], W[d * DOUT_K + lane], acc);
    const float bs = acc * LOG2E;
    const unsigned short hs = f32_bf16_rne(bs);
    const float hf = bf16_f32(hs);
    const unsigned short ls = f32_bf16_rne(bs - hf);
    bh[row * DOUT_K + lane] = hs;
    bl[row * DOUT_K + lane] = ls;
    float t = fmaxf(bs, 0.f);
    #pragma unroll
    for (int m = 1; m < 64; m <<= 1) t += __shfl_xor(t, m, 64);
    if (lane == 0) off2[row] = t;
}

// ---------------------------------------------------------------------------
// Kernel 2: pack adjacency into MFMA A-fragment order, bf16 hi/lo (unchanged).
// chunk c, ks: lane l holds adj[k = ks*32 + (l>>4)*8 + i][c*16 + (l&15)]
// ---------------------------------------------------------------------------
__global__ __launch_bounds__(256) void k_pack(
    const float* __restrict__ A,
    unsigned short* __restrict__ ahp, unsigned short* __restrict__ alp)
{
    const int wid   = blockIdx.x * 4 + (threadIdx.x >> 6);  // 0..2047
    const int lane  = threadIdx.x & 63;
    const int chunk = wid >> 1, ks = wid & 1;
    const int col   = chunk * 16 + (lane & 15);
    const int kb    = ks * 32 + ((lane >> 4) * 8);
    const size_t base = ((size_t)(chunk * 2 + ks) * 64 + lane) * 8;
    #pragma unroll
    for (int i = 0; i < 8; ++i) {
        const float a = A[(size_t)(kb + i) * M_COLS + col];
        const unsigned short hs = f32_bf16_rne(a);
        ahp[base + i] = hs;
        alp[base + i] = f32_bf16_rne(a - bf16_f32(hs));
    }
}

// ---------------------------------------------------------------------------
// k_denom / k_final: 3-blocks/CU occupancy structure.
//   grid 768 = 256 row-groups x 3 col-groups; block = 256 thr (4 waves),
//   64 rows/block (rt=4), __launch_bounds__(256,3) -> VGPR cap 170.
//   cg chunk range: s = 341*cg + (cg!=0), e = 341*cg + 342  (342/341/341).
//   Wave w gets [s + w*q + min(w,r), +q + (w<r)) with q=n/4, r=n%4.
//   Denominators via partial[3][N_ROWS] (deterministic, no atomics).
// ---------------------------------------------------------------------------
#define LOAD_STATIONARY()                                                   \
    short8 bHf[4][2], bLf[4][2];                                            \
    _Pragma("unroll")                                                       \
    for (int rt = 0; rt < 4; ++rt)                                          \
        _Pragma("unroll")                                                   \
        for (int ks = 0; ks < 2; ++ks) {                                    \
            const size_t o = (size_t)(r0 + rt * 16 + lrow) * DOUT_K         \
                           + ks * 32 + lgrp * 8;                            \
            bHf[rt][ks] = *reinterpret_cast<const short8*>(bh + o);         \
            bLf[rt][ks] = *reinterpret_cast<const short8*>(bl + o);         \
        }

#define WAVE_RANGE()                                                        \
    const int cg = blockIdx.x % 3;                                          \
    const int rb = blockIdx.x / 3;                                          \
    const int r0 = rb * 64;                                                 \
    const int s  = 341 * cg + (cg != 0);                                    \
    const int n  = 342 - (cg != 0);                                         \
    const int q  = n >> 2, r = n & 3;                                       \
    const int c0 = s + wave * q + (wave < r ? wave : r);                    \
    const int cn = q + (wave < r ? 1 : 0);

__global__ __launch_bounds__(256, 3) void k_denom(
    const unsigned short* __restrict__ bh, const unsigned short* __restrict__ bl,
    const unsigned short* __restrict__ ahp, const unsigned short* __restrict__ alp,
    const float* __restrict__ off2, float* __restrict__ partial)
{
    __shared__ float lds[4][64];
    const int wave = threadIdx.x >> 6;
    const int lane = threadIdx.x & 63;
    const int lrow = lane & 15;
    const int lgrp = lane >> 4;
    WAVE_RANGE();

    LOAD_STATIONARY();
    float negoff[4];
    #pragma unroll
    for (int rt = 0; rt < 4; ++rt)
        negoff[rt] = -off2[r0 + rt * 16 + lrow];

    float lsum[4] = {0.f, 0.f, 0.f, 0.f};

#define LOADA(H0, H1, c) {                                                  \
    const size_t _b = (size_t)((c) * 2) * 512 + lane * 8;                   \
    H0 = *reinterpret_cast<const short8*>(ahp + _b);                        \
    H1 = *reinterpret_cast<const short8*>(ahp + _b + 512); }

#define BODY1(H0, H1)                                                       \
    _Pragma("unroll")                                                       \
    for (int rt = 0; rt < 4; ++rt) {                                        \
        f32x4 acc = { negoff[rt], negoff[rt], negoff[rt], negoff[rt] };     \
        acc = MFMA16(H0, bHf[rt][0], acc, 0, 0, 0);                         \
        acc = MFMA16(H1, bHf[rt][1], acc, 0, 0, 0);                         \
        acc = MFMA16(H0, bLf[rt][0], acc, 0, 0, 0);                         \
        acc = MFMA16(H1, bLf[rt][1], acc, 0, 0, 0);                         \
        lsum[rt] += (EXP2F(acc[0]) + EXP2F(acc[1]))                         \
                  + (EXP2F(acc[2]) + EXP2F(acc[3])); }

    short8 cH0, cH1, nH0, nH1;
    const int even = cn & ~1;
    LOADA(cH0, cH1, c0);
    for (int j = 0; j < even; j += 2) {
        LOADA(nH0, nH1, c0 + j + 1);
        BODY1(cH0, cH1);
        LOADA(cH0, cH1, c0 + ((j + 2 < cn) ? j + 2 : j + 1));
        BODY1(nH0, nH1);
    }
    if (cn & 1) BODY1(cH0, cH1);   // cur holds chunk cn-1 from last guarded load
#undef LOADA
#undef BODY1

    #pragma unroll
    for (int rt = 0; rt < 4; ++rt) {
        float v = lsum[rt];
        v += __shfl_xor(v, 16, 64);
        v += __shfl_xor(v, 32, 64);
        lsum[rt] = v;
    }
    if (lgrp == 0) {
        #pragma unroll
        for (int rt = 0; rt < 4; ++rt)
            lds[wave][rt * 16 + lrow] = lsum[rt];
    }
    __syncthreads();
    if (wave == 0) {
        const float tot = (lds[0][lane] + lds[1][lane])
                        + (lds[2][lane] + lds[3][lane]);
        partial[(size_t)cg * N_ROWS + r0 + lane] = tot;
    }
}

__global__ __launch_bounds__(256, 3) void k_final(
    const unsigned short* __restrict__ bh, const unsigned short* __restrict__ bl,
    const unsigned short* __restrict__ ahp, const unsigned short* __restrict__ alp,
    const float* __restrict__ off2, const float* __restrict__ partial,
    float* __restrict__ out)
{
    const int wave = threadIdx.x >> 6;
    const int lane = threadIdx.x & 63;
    const int lrow = lane & 15;
    const int lgrp = lane >> 4;
    WAVE_RANGE();

    LOAD_STATIONARY();
    float base2[4];
    #pragma unroll
    for (int rt = 0; rt < 4; ++rt) {
        const int row = r0 + rt * 16 + lrow;
        const float tot = partial[row] + partial[N_ROWS + row]
                        + partial[2 * N_ROWS + row];
        base2[rt] = -off2[row] - LOG2F(tot);
    }

#define LOADB(H0, H1, L0, L1, c) {                                          \
    const size_t _b = (size_t)((c) * 2) * 512 + lane * 8;                   \
    H0 = *reinterpret_cast<const short8*>(ahp + _b);                        \
    H1 = *reinterpret_cast<const short8*>(ahp + _b + 512);                  \
    L0 = *reinterpret_cast<const short8*>(alp + _b);                        \
    L1 = *reinterpret_cast<const short8*>(alp + _b + 512); }

#define BODY2(H0, H1, L0, L1, c)                                            \
    _Pragma("unroll")                                                       \
    for (int rt = 0; rt < 4; ++rt) {                                        \
        f32x4 acc = { base2[rt], base2[rt], base2[rt], base2[rt] };         \
        acc = MFMA16(H0, bHf[rt][0], acc, 0, 0, 0);                         \
        acc = MFMA16(H1, bHf[rt][1], acc, 0, 0, 0);                         \
        acc = MFMA16(L0, bHf[rt][0], acc, 0, 0, 0);                         \
        acc = MFMA16(L1, bHf[rt][1], acc, 0, 0, 0);                         \
        acc = MFMA16(H0, bLf[rt][0], acc, 0, 0, 0);                         \
        acc = MFMA16(H1, bLf[rt][1], acc, 0, 0, 0);                         \
        f32x4 o4 = { EXP2F(acc[0]), EXP2F(acc[1]),                          \
                     EXP2F(acc[2]), EXP2F(acc[3]) };                        \
        const size_t _o = (size_t)(r0 + rt * 16 + lrow) * M_COLS            \
                        + (size_t)(c) * 16 + lgrp * 4;                      \
        __builtin_nontemporal_store(o4, reinterpret_cast<f32x4*>(out + _o)); }

    short8 cH0, cH1, cL0, cL1, nH0, nH1, nL0, nL1;
    const int even = cn & ~1;
    LOADB(cH0, cH1, cL0, cL1, c0);
    for (int j = 0; j < even; j += 2) {
        LOADB(nH0, nH1, nL0, nL1, c0 + j + 1);
        BODY2(cH0, cH1, cL0, cL1, c0 + j);
        LOADB(cH0, cH1, cL0, cL1, c0 + ((j + 2 < cn) ? j + 2 : j + 1));
        BODY2(nH0, nH1, nL0, nL1, c0 + j + 1);
    }
    if (cn & 1) BODY2(cH0, cH1, cL0, cL1, c0 + cn - 1);
#undef LOADB
#undef BODY2
}

extern "C" void kernel_launch(void* const* d_in, const int* in_sizes, int n_in,
                              void* d_out, int out_size, void* d_ws, size_t ws_size,
                              hipStream_t stream) {
    const float* X = (const float*)d_in[0];   // [16384, 256]
    const float* A = (const float*)d_in[1];   // [64, 16384]
    const float* W = (const float*)d_in[2];   // [256, 64]
    float* out = (float*)d_out;               // [16384, 16384]

    char* wsb = (char*)d_ws;
    float*          off2    = (float*)wsb;                                  // 64 KB
    unsigned short* bh      = (unsigned short*)(wsb + (1u << 16));          // 2 MB
    unsigned short* bl      = (unsigned short*)(wsb + (1u << 16) + 1u * (1u << 21));
    unsigned short* ahp     = (unsigned short*)(wsb + (1u << 16) + 2u * (1u << 21));
    unsigned short* alp     = (unsigned short*)(wsb + (1u << 16) + 3u * (1u << 21));
    float*          partial = (float*)(wsb + (1u << 16) + 4u * (1u << 21)); // 192 KB

    hipLaunchKernelGGL(k_before, dim3(N_ROWS / 4), dim3(256), 0, stream, X, W, off2, bh, bl);
    hipLaunchKernelGGL(k_pack,   dim3(512),        dim3(256), 0, stream, A, ahp, alp);
    hipLaunchKernelGGL(k_denom,  dim3(768),        dim3(256), 0, stream, bh, bl, ahp, alp, off2, partial);
    hipLaunchKernelGGL(k_final,  dim3(768),        dim3(256), 0, stream, bh, bl, ahp, alp, off2, partial, out);
}

// Round 9
// 486.328 us; speedup vs baseline: 1.0739x; 1.0739x over previous
//
#include <hip/hip_runtime.h>
#include <hip/hip_bf16.h>

#define N_ROWS 16384
#define DIN_K  256
#define DOUT_K 64
#define M_COLS 16384
#define LOG2E  1.4426950408889634f

typedef __attribute__((ext_vector_type(8))) short short8;
typedef __attribute__((ext_vector_type(4))) float f32x4;

#define MFMA16 __builtin_amdgcn_mfma_f32_16x16x32_bf16
#define EXP2F  __builtin_amdgcn_exp2f
#define LOG2F  __builtin_amdgcn_logf

__device__ inline unsigned short f32_bf16_rne(float x) {
    unsigned u = __builtin_bit_cast(unsigned, x);
    u += 0x7fffu + ((u >> 16) & 1u);
    return (unsigned short)(u >> 16);
}
__device__ inline float bf16_f32(unsigned short h) {
    unsigned u = ((unsigned)h) << 16;
    return __builtin_bit_cast(float, u);
}

// ---------------------------------------------------------------------------
// Kernel 1: before = (X @ W) * log2(e); split to bf16 hi/lo; per-row exp bound
// ---------------------------------------------------------------------------
__global__ __launch_bounds__(256) void k_before(
    const float* __restrict__ X, const float* __restrict__ W,
    float* __restrict__ off2,
    unsigned short* __restrict__ bh, unsigned short* __restrict__ bl)
{
    const int row  = blockIdx.x * 4 + (threadIdx.x >> 6);
    const int lane = threadIdx.x & 63;
    const float* xr = X + (size_t)row * DIN_K;
    float acc = 0.f;
    #pragma unroll 8
    for (int d = 0; d < DIN_K; ++d)
        acc = fmaf(xr[d], W[d * DOUT_K + lane], acc);
    const float bs = acc * LOG2E;
    const unsigned short hs = f32_bf16_rne(bs);
    const float hf = bf16_f32(hs);
    const unsigned short ls = f32_bf16_rne(bs - hf);
    bh[row * DOUT_K + lane] = hs;
    bl[row * DOUT_K + lane] = ls;
    float t = fmaxf(bs, 0.f);
    #pragma unroll
    for (int m = 1; m < 64; m <<= 1) t += __shfl_xor(t, m, 64);
    if (lane == 0) off2[row] = t;
}

// ---------------------------------------------------------------------------
// Kernel 2: pack adjacency into MFMA A-fragment order, bf16 hi/lo (unchanged).
// chunk c, ks: lane l holds adj[k = ks*32 + (l>>4)*8 + i][c*16 + (l&15)]
// ---------------------------------------------------------------------------
__global__ __launch_bounds__(256) void k_pack(
    const float* __restrict__ A,
    unsigned short* __restrict__ ahp, unsigned short* __restrict__ alp)
{
    const int wid   = blockIdx.x * 4 + (threadIdx.x >> 6);  // 0..2047
    const int lane  = threadIdx.x & 63;
    const int chunk = wid >> 1, ks = wid & 1;
    const int col   = chunk * 16 + (lane & 15);
    const int kb    = ks * 32 + ((lane >> 4) * 8);
    const size_t base = ((size_t)(chunk * 2 + ks) * 64 + lane) * 8;
    #pragma unroll
    for (int i = 0; i < 8; ++i) {
        const float a = A[(size_t)(kb + i) * M_COLS + col];
        const unsigned short hs = f32_bf16_rne(a);
        ahp[base + i] = hs;
        alp[base + i] = f32_bf16_rne(a - bf16_f32(hs));
    }
}

// ---------------------------------------------------------------------------
// Kernel 3: fused scores + softmax (R6 structure + per-wave rotated chunk
// order to decorrelate HBM channel phases across the machine).
//   256 blocks x 8 waves; block owns 64 rows (rt=4); wave owns 128 chunks,
//   processed in order (j + rot) & 127, rot = hash(block, wave).
//   Pass 1: 2-term (aH x (bH+bL)), ahp-only loads.
//   Pass 2: full 3-term, f32x4 nontemporal stores.
// ---------------------------------------------------------------------------
__global__ __launch_bounds__(512, 2) void k_main(
    const unsigned short* __restrict__ bh, const unsigned short* __restrict__ bl,
    const unsigned short* __restrict__ ahp, const unsigned short* __restrict__ alp,
    const float* __restrict__ off2, float* __restrict__ out)
{
    __shared__ float lds[8][64];
    const int wave = threadIdx.x >> 6;
    const int lane = threadIdx.x & 63;
    const int lrow = lane & 15;   // out-row within tile (D col)
    const int lgrp = lane >> 4;   // out-col quad (D row group)
    const int r0   = blockIdx.x * 64;
    const int rot  = (((blockIdx.x << 3) | wave) * 53) & 127;
    const int cbase = wave * 128;

#define CIDX(j) (cbase + (((j) + rot) & 127))

    // Stationary before^T fragments (B operand), 4 row-tiles, hi/lo.
    short8 bHf[4][2], bLf[4][2];
    #pragma unroll
    for (int rt = 0; rt < 4; ++rt)
        #pragma unroll
        for (int ks = 0; ks < 2; ++ks) {
            const size_t o = (size_t)(r0 + rt * 16 + lrow) * DOUT_K + ks * 32 + lgrp * 8;
            bHf[rt][ks] = *reinterpret_cast<const short8*>(bh + o);
            bLf[rt][ks] = *reinterpret_cast<const short8*>(bl + o);
        }

    float negoff[4];
    #pragma unroll
    for (int rt = 0; rt < 4; ++rt)
        negoff[rt] = -off2[r0 + rt * 16 + lrow];

    float lsum[4] = {0.f, 0.f, 0.f, 0.f};

#define LOADA(H0, H1, c) {                                                  \
    const size_t _b = (size_t)((c) * 2) * 512 + lane * 8;                   \
    H0 = *reinterpret_cast<const short8*>(ahp + _b);                        \
    H1 = *reinterpret_cast<const short8*>(ahp + _b + 512); }

#define LOADB(H0, H1, L0, L1, c) {                                          \
    const size_t _b = (size_t)((c) * 2) * 512 + lane * 8;                   \
    H0 = *reinterpret_cast<const short8*>(ahp + _b);                        \
    H1 = *reinterpret_cast<const short8*>(ahp + _b + 512);                  \
    L0 = *reinterpret_cast<const short8*>(alp + _b);                        \
    L1 = *reinterpret_cast<const short8*>(alp + _b + 512); }

#define BODY1(H0, H1)                                                       \
    _Pragma("unroll")                                                       \
    for (int rt = 0; rt < 4; ++rt) {                                        \
        f32x4 acc = { negoff[rt], negoff[rt], negoff[rt], negoff[rt] };     \
        acc = MFMA16(H0, bHf[rt][0], acc, 0, 0, 0);                         \
        acc = MFMA16(H1, bHf[rt][1], acc, 0, 0, 0);                         \
        acc = MFMA16(H0, bLf[rt][0], acc, 0, 0, 0);                         \
        acc = MFMA16(H1, bLf[rt][1], acc, 0, 0, 0);                         \
        lsum[rt] += (EXP2F(acc[0]) + EXP2F(acc[1]))                         \
                  + (EXP2F(acc[2]) + EXP2F(acc[3])); }

    short8 cH0, cH1, cL0, cL1, nH0, nH1, nL0, nL1;

    // ---- pass 1: denominators (2-term, ahp-only, rotated ping-pong) ----
    LOADA(cH0, cH1, CIDX(0));
    for (int j = 0; j < 128; j += 2) {
        LOADA(nH0, nH1, CIDX(j + 1));
        BODY1(cH0, cH1);
        LOADA(cH0, cH1, CIDX(j + 2));
        BODY1(nH0, nH1);
    }

    // lane's lsum[rt] covers its col-quads; reduce over the 4 lane-groups
    #pragma unroll
    for (int rt = 0; rt < 4; ++rt) {
        float v = lsum[rt];
        v += __shfl_xor(v, 16, 64);
        v += __shfl_xor(v, 32, 64);
        lsum[rt] = v;
    }
    if (lgrp == 0) {
        #pragma unroll
        for (int rt = 0; rt < 4; ++rt)
            lds[wave][rt * 16 + lrow] = lsum[rt];
    }
    __syncthreads();

    float base2[4];
    #pragma unroll
    for (int rt = 0; rt < 4; ++rt) {
        const int rl = rt * 16 + lrow;
        float tot = ((lds[0][rl] + lds[1][rl]) + (lds[2][rl] + lds[3][rl]))
                  + ((lds[4][rl] + lds[5][rl]) + (lds[6][rl] + lds[7][rl]));
        base2[rt] = negoff[rt] - LOG2F(tot);
    }

#define BODY2(H0, H1, L0, L1, c)                                            \
    _Pragma("unroll")                                                       \
    for (int rt = 0; rt < 4; ++rt) {                                        \
        f32x4 acc = { base2[rt], base2[rt], base2[rt], base2[rt] };         \
        acc = MFMA16(H0, bHf[rt][0], acc, 0, 0, 0);                         \
        acc = MFMA16(H1, bHf[rt][1], acc, 0, 0, 0);                         \
        acc = MFMA16(L0, bHf[rt][0], acc, 0, 0, 0);                         \
        acc = MFMA16(L1, bHf[rt][1], acc, 0, 0, 0);                         \
        acc = MFMA16(H0, bLf[rt][0], acc, 0, 0, 0);                         \
        acc = MFMA16(H1, bLf[rt][1], acc, 0, 0, 0);                         \
        f32x4 o4 = { EXP2F(acc[0]), EXP2F(acc[1]),                          \
                     EXP2F(acc[2]), EXP2F(acc[3]) };                        \
        const size_t _o = (size_t)(r0 + rt * 16 + lrow) * M_COLS            \
                        + (size_t)(c) * 16 + lgrp * 4;                      \
        __builtin_nontemporal_store(o4, reinterpret_cast<f32x4*>(out + _o)); }

    // ---- pass 2: recompute scores (3-term), rotated order, write softmax ----
    LOADB(cH0, cH1, cL0, cL1, CIDX(0));
    for (int j = 0; j < 128; j += 2) {
        LOADB(nH0, nH1, nL0, nL1, CIDX(j + 1));
        BODY2(cH0, cH1, cL0, cL1, CIDX(j));
        LOADB(cH0, cH1, cL0, cL1, CIDX(j + 2));
        BODY2(nH0, nH1, nL0, nL1, CIDX(j + 1));
    }
#undef CIDX
#undef LOADA
#undef LOADB
#undef BODY1
#undef BODY2
}

extern "C" void kernel_launch(void* const* d_in, const int* in_sizes, int n_in,
                              void* d_out, int out_size, void* d_ws, size_t ws_size,
                              hipStream_t stream) {
    const float* X = (const float*)d_in[0];   // [16384, 256]
    const float* A = (const float*)d_in[1];   // [64, 16384]
    const float* W = (const float*)d_in[2];   // [256, 64]
    float* out = (float*)d_out;               // [16384, 16384]

    char* wsb = (char*)d_ws;
    float*          off2 = (float*)wsb;                                   // 64 KB
    unsigned short* bh   = (unsigned short*)(wsb + (1u << 16));           // 2 MB
    unsigned short* bl   = (unsigned short*)(wsb + (1u << 16) + (1u << 21));
    unsigned short* ahp  = (unsigned short*)(wsb + (1u << 16) + 2u * (1u << 21));
    unsigned short* alp  = (unsigned short*)(wsb + (1u << 16) + 3u * (1u << 21));

    hipLaunchKernelGGL(k_before, dim3(N_ROWS / 4), dim3(256), 0, stream, X, W, off2, bh, bl);
    hipLaunchKernelGGL(k_pack,   dim3(512),        dim3(256), 0, stream, A, ahp, alp);
    hipLaunchKernelGGL(k_main,   dim3(256),        dim3(512), 0, stream, bh, bl, ahp, alp, off2, out);
}

// Round 10
// 482.162 us; speedup vs baseline: 1.0832x; 1.0086x over previous
//
#include <hip/hip_runtime.h>
#include <hip/hip_bf16.h>

#define N_ROWS 16384
#define DIN_K  256
#define DOUT_K 64
#define M_COLS 16384
#define LOG2E  1.4426950408889634f

typedef __attribute__((ext_vector_type(8))) short short8;
typedef __attribute__((ext_vector_type(4))) float f32x4;

#define MFMA16 __builtin_amdgcn_mfma_f32_16x16x32_bf16
#define EXP2F  __builtin_amdgcn_exp2f
#define LOG2F  __builtin_amdgcn_logf

__device__ inline unsigned short f32_bf16_rne(float x) {
    unsigned u = __builtin_bit_cast(unsigned, x);
    u += 0x7fffu + ((u >> 16) & 1u);
    return (unsigned short)(u >> 16);
}
__device__ inline float bf16_f32(unsigned short h) {
    unsigned u = ((unsigned)h) << 16;
    return __builtin_bit_cast(float, u);
}

// ---------------------------------------------------------------------------
// Kernel 1: before = (X @ W) * log2(e); split to bf16 hi/lo; per-row exp bound
// ---------------------------------------------------------------------------
__global__ __launch_bounds__(256) void k_before(
    const float* __restrict__ X, const float* __restrict__ W,
    float* __restrict__ off2,
    unsigned short* __restrict__ bh, unsigned short* __restrict__ bl)
{
    const int row  = blockIdx.x * 4 + (threadIdx.x >> 6);
    const int lane = threadIdx.x & 63;
    const float* xr = X + (size_t)row * DIN_K;
    float acc = 0.f;
    #pragma unroll 8
    for (int d = 0; d < DIN_K; ++d)
        acc = fmaf(xr[d], W[d * DOUT_K + lane], acc);
    const float bs = acc * LOG2E;
    const unsigned short hs = f32_bf16_rne(bs);
    const float hf = bf16_f32(hs);
    const unsigned short ls = f32_bf16_rne(bs - hf);
    bh[row * DOUT_K + lane] = hs;
    bl[row * DOUT_K + lane] = ls;
    float t = fmaxf(bs, 0.f);
    #pragma unroll
    for (int m = 1; m < 64; m <<= 1) t += __shfl_xor(t, m, 64);
    if (lane == 0) off2[row] = t;
}

// ---------------------------------------------------------------------------
// Kernel 2: pack adjacency into MFMA A-fragment order, bf16 hi/lo (unchanged).
// chunk c, ks: lane l holds adj[k = ks*32 + (l>>4)*8 + i][c*16 + (l&15)]
// ---------------------------------------------------------------------------
__global__ __launch_bounds__(256) void k_pack(
    const float* __restrict__ A,
    unsigned short* __restrict__ ahp, unsigned short* __restrict__ alp)
{
    const int wid   = blockIdx.x * 4 + (threadIdx.x >> 6);  // 0..2047
    const int lane  = threadIdx.x & 63;
    const int chunk = wid >> 1, ks = wid & 1;
    const int col   = chunk * 16 + (lane & 15);
    const int kb    = ks * 32 + ((lane >> 4) * 8);
    const size_t base = ((size_t)(chunk * 2 + ks) * 64 + lane) * 8;
    #pragma unroll
    for (int i = 0; i < 8; ++i) {
        const float a = A[(size_t)(kb + i) * M_COLS + col];
        const unsigned short hs = f32_bf16_rne(a);
        ahp[base + i] = hs;
        alp[base + i] = f32_bf16_rne(a - bf16_f32(hs));
    }
}

// ---------------------------------------------------------------------------
// Kernel 3: fused scores + softmax (R9 structure; stores switched from
// nontemporal to PLAIN cached stores -> L2 write-combining / full-line
// writeback. Single-variable A/B vs R9.)
//   256 blocks x 8 waves; block owns 64 rows (rt=4); wave owns 128 chunks,
//   processed in order (j + rot) & 127, rot = hash(block, wave).
//   Pass 1: 2-term (aH x (bH+bL)), ahp-only loads.
//   Pass 2: full 3-term, f32x4 plain stores.
// ---------------------------------------------------------------------------
__global__ __launch_bounds__(512, 2) void k_main(
    const unsigned short* __restrict__ bh, const unsigned short* __restrict__ bl,
    const unsigned short* __restrict__ ahp, const unsigned short* __restrict__ alp,
    const float* __restrict__ off2, float* __restrict__ out)
{
    __shared__ float lds[8][64];
    const int wave = threadIdx.x >> 6;
    const int lane = threadIdx.x & 63;
    const int lrow = lane & 15;   // out-row within tile (D col)
    const int lgrp = lane >> 4;   // out-col quad (D row group)
    const int r0   = blockIdx.x * 64;
    const int rot  = (((blockIdx.x << 3) | wave) * 53) & 127;
    const int cbase = wave * 128;

#define CIDX(j) (cbase + (((j) + rot) & 127))

    // Stationary before^T fragments (B operand), 4 row-tiles, hi/lo.
    short8 bHf[4][2], bLf[4][2];
    #pragma unroll
    for (int rt = 0; rt < 4; ++rt)
        #pragma unroll
        for (int ks = 0; ks < 2; ++ks) {
            const size_t o = (size_t)(r0 + rt * 16 + lrow) * DOUT_K + ks * 32 + lgrp * 8;
            bHf[rt][ks] = *reinterpret_cast<const short8*>(bh + o);
            bLf[rt][ks] = *reinterpret_cast<const short8*>(bl + o);
        }

    float negoff[4];
    #pragma unroll
    for (int rt = 0; rt < 4; ++rt)
        negoff[rt] = -off2[r0 + rt * 16 + lrow];

    float lsum[4] = {0.f, 0.f, 0.f, 0.f};

#define LOADA(H0, H1, c) {                                                  \
    const size_t _b = (size_t)((c) * 2) * 512 + lane * 8;                   \
    H0 = *reinterpret_cast<const short8*>(ahp + _b);                        \
    H1 = *reinterpret_cast<const short8*>(ahp + _b + 512); }

#define LOADB(H0, H1, L0, L1, c) {                                          \
    const size_t _b = (size_t)((c) * 2) * 512 + lane * 8;                   \
    H0 = *reinterpret_cast<const short8*>(ahp + _b);                        \
    H1 = *reinterpret_cast<const short8*>(ahp + _b + 512);                  \
    L0 = *reinterpret_cast<const short8*>(alp + _b);                        \
    L1 = *reinterpret_cast<const short8*>(alp + _b + 512); }

#define BODY1(H0, H1)                                                       \
    _Pragma("unroll")                                                       \
    for (int rt = 0; rt < 4; ++rt) {                                        \
        f32x4 acc = { negoff[rt], negoff[rt], negoff[rt], negoff[rt] };     \
        acc = MFMA16(H0, bHf[rt][0], acc, 0, 0, 0);                         \
        acc = MFMA16(H1, bHf[rt][1], acc, 0, 0, 0);                         \
        acc = MFMA16(H0, bLf[rt][0], acc, 0, 0, 0);                         \
        acc = MFMA16(H1, bLf[rt][1], acc, 0, 0, 0);                         \
        lsum[rt] += (EXP2F(acc[0]) + EXP2F(acc[1]))                         \
                  + (EXP2F(acc[2]) + EXP2F(acc[3])); }

    short8 cH0, cH1, cL0, cL1, nH0, nH1, nL0, nL1;

    // ---- pass 1: denominators (2-term, ahp-only, rotated ping-pong) ----
    LOADA(cH0, cH1, CIDX(0));
    for (int j = 0; j < 128; j += 2) {
        LOADA(nH0, nH1, CIDX(j + 1));
        BODY1(cH0, cH1);
        LOADA(cH0, cH1, CIDX(j + 2));
        BODY1(nH0, nH1);
    }

    // lane's lsum[rt] covers its col-quads; reduce over the 4 lane-groups
    #pragma unroll
    for (int rt = 0; rt < 4; ++rt) {
        float v = lsum[rt];
        v += __shfl_xor(v, 16, 64);
        v += __shfl_xor(v, 32, 64);
        lsum[rt] = v;
    }
    if (lgrp == 0) {
        #pragma unroll
        for (int rt = 0; rt < 4; ++rt)
            lds[wave][rt * 16 + lrow] = lsum[rt];
    }
    __syncthreads();

    float base2[4];
    #pragma unroll
    for (int rt = 0; rt < 4; ++rt) {
        const int rl = rt * 16 + lrow;
        float tot = ((lds[0][rl] + lds[1][rl]) + (lds[2][rl] + lds[3][rl]))
                  + ((lds[4][rl] + lds[5][rl]) + (lds[6][rl] + lds[7][rl]));
        base2[rt] = negoff[rt] - LOG2F(tot);
    }

#define BODY2(H0, H1, L0, L1, c)                                            \
    _Pragma("unroll")                                                       \
    for (int rt = 0; rt < 4; ++rt) {                                        \
        f32x4 acc = { base2[rt], base2[rt], base2[rt], base2[rt] };         \
        acc = MFMA16(H0, bHf[rt][0], acc, 0, 0, 0);                         \
        acc = MFMA16(H1, bHf[rt][1], acc, 0, 0, 0);                         \
        acc = MFMA16(L0, bHf[rt][0], acc, 0, 0, 0);                         \
        acc = MFMA16(L1, bHf[rt][1], acc, 0, 0, 0);                         \
        acc = MFMA16(H0, bLf[rt][0], acc, 0, 0, 0);                         \
        acc = MFMA16(H1, bLf[rt][1], acc, 0, 0, 0);                         \
        f32x4 o4 = { EXP2F(acc[0]), EXP2F(acc[1]),                          \
                     EXP2F(acc[2]), EXP2F(acc[3]) };                        \
        const size_t _o = (size_t)(r0 + rt * 16 + lrow) * M_COLS            \
                        + (size_t)(c) * 16 + lgrp * 4;                      \
        *reinterpret_cast<f32x4*>(out + _o) = o4; }

    // ---- pass 2: recompute scores (3-term), rotated order, write softmax ----
    LOADB(cH0, cH1, cL0, cL1, CIDX(0));
    for (int j = 0; j < 128; j += 2) {
        LOADB(nH0, nH1, nL0, nL1, CIDX(j + 1));
        BODY2(cH0, cH1, cL0, cL1, CIDX(j));
        LOADB(cH0, cH1, cL0, cL1, CIDX(j + 2));
        BODY2(nH0, nH1, nL0, nL1, CIDX(j + 1));
    }
#undef CIDX
#undef LOADA
#undef LOADB
#undef BODY1
#undef BODY2
}

extern "C" void kernel_launch(void* const* d_in, const int* in_sizes, int n_in,
                              void* d_out, int out_size, void* d_ws, size_t ws_size,
                              hipStream_t stream) {
    const float* X = (const float*)d_in[0];   // [16384, 256]
    const float* A = (const float*)d_in[1];   // [64, 16384]
    const float* W = (const float*)d_in[2];   // [256, 64]
    float* out = (float*)d_out;               // [16384, 16384]

    char* wsb = (char*)d_ws;
    float*          off2 = (float*)wsb;                                   // 64 KB
    unsigned short* bh   = (unsigned short*)(wsb + (1u << 16));           // 2 MB
    unsigned short* bl   = (unsigned short*)(wsb + (1u << 16) + (1u << 21));
    unsigned short* ahp  = (unsigned short*)(wsb + (1u << 16) + 2u * (1u << 21));
    unsigned short* alp  = (unsigned short*)(wsb + (1u << 16) + 3u * (1u << 21));

    hipLaunchKernelGGL(k_before, dim3(N_ROWS / 4), dim3(256), 0, stream, X, W, off2, bh, bl);
    hipLaunchKernelGGL(k_pack,   dim3(512),        dim3(256), 0, stream, A, ahp, alp);
    hipLaunchKernelGGL(k_main,   dim3(256),        dim3(512), 0, stream, bh, bl, ahp, alp, off2, out);
}

// Round 11
// 307.526 us; speedup vs baseline: 1.6983x; 1.5679x over previous
//
#include <hip/hip_runtime.h>
#include <hip/hip_bf16.h>

#define N_ROWS 16384
#define DIN_K  256
#define DOUT_K 64
#define M_COLS 16384
#define LOG2E  1.4426950408889634f

typedef __attribute__((ext_vector_type(8))) short short8;
typedef __attribute__((ext_vector_type(4))) float f32x4;

#define MFMA16 __builtin_amdgcn_mfma_f32_16x16x32_bf16
#define EXP2F  __builtin_amdgcn_exp2f
#define LOG2F  __builtin_amdgcn_logf

__device__ inline unsigned short f32_bf16_rne(float x) {
    unsigned u = __builtin_bit_cast(unsigned, x);
    u += 0x7fffu + ((u >> 16) & 1u);
    return (unsigned short)(u >> 16);
}
__device__ inline float bf16_f32(unsigned short h) {
    unsigned u = ((unsigned)h) << 16;
    return __builtin_bit_cast(float, u);
}

// ---------------------------------------------------------------------------
// Kernel 1: before = (X @ W) * log2(e); split to bf16 hi/lo; per-row exp bound
// ---------------------------------------------------------------------------
__global__ __launch_bounds__(256) void k_before(
    const float* __restrict__ X, const float* __restrict__ W,
    float* __restrict__ off2,
    unsigned short* __restrict__ bh, unsigned short* __restrict__ bl)
{
    const int row  = blockIdx.x * 4 + (threadIdx.x >> 6);
    const int lane = threadIdx.x & 63;
    const float* xr = X + (size_t)row * DIN_K;
    float acc = 0.f;
    #pragma unroll 8
    for (int d = 0; d < DIN_K; ++d)
        acc = fmaf(xr[d], W[d * DOUT_K + lane], acc);
    const float bs = acc * LOG2E;
    const unsigned short hs = f32_bf16_rne(bs);
    const float hf = bf16_f32(hs);
    const unsigned short ls = f32_bf16_rne(bs - hf);
    bh[row * DOUT_K + lane] = hs;
    bl[row * DOUT_K + lane] = ls;
    float t = fmaxf(bs, 0.f);
    #pragma unroll
    for (int m = 1; m < 64; m <<= 1) t += __shfl_xor(t, m, 64);
    if (lane == 0) off2[row] = t;
}

// ---------------------------------------------------------------------------
// Kernel 2: pack adjacency into MFMA A-fragment order, bf16 hi/lo (unchanged).
// chunk c, ks: lane l holds adj[k = ks*32 + (l>>4)*8 + i][c*16 + (l&15)]
// ---------------------------------------------------------------------------
__global__ __launch_bounds__(256) void k_pack(
    const float* __restrict__ A,
    unsigned short* __restrict__ ahp, unsigned short* __restrict__ alp)
{
    const int wid   = blockIdx.x * 4 + (threadIdx.x >> 6);  // 0..2047
    const int lane  = threadIdx.x & 63;
    const int chunk = wid >> 1, ks = wid & 1;
    const int col   = chunk * 16 + (lane & 15);
    const int kb    = ks * 32 + ((lane >> 4) * 8);
    const size_t base = ((size_t)(chunk * 2 + ks) * 64 + lane) * 8;
    #pragma unroll
    for (int i = 0; i < 8; ++i) {
        const float a = A[(size_t)(kb + i) * M_COLS + col];
        const unsigned short hs = f32_bf16_rne(a);
        ahp[base + i] = hs;
        alp[base + i] = f32_bf16_rne(a - bf16_f32(hs));
    }
}

// ---------------------------------------------------------------------------
// Kernel 3: fused scores + softmax.
//   Pass 1 (unchanged R10): 2-term denominators, per-wave rotated streaming.
//   Pass 2 (NEW): 64 slabs of 64 rows x 256 cols. Each wave computes its 2
//   chunks of the slab, ds_writes exp2 results into a 64x260 LDS tile,
//   barrier, then stores 8 FULL rows as 1KB-contiguous bursts (one DRAM page
//   per instruction). Per-block slab rotation decorrelates columns.
// ---------------------------------------------------------------------------
__global__ __launch_bounds__(512, 2) void k_main(
    const unsigned short* __restrict__ bh, const unsigned short* __restrict__ bl,
    const unsigned short* __restrict__ ahp, const unsigned short* __restrict__ alp,
    const float* __restrict__ off2, float* __restrict__ out)
{
    __shared__ float lds[8][64];
    __shared__ float sout[64 * 260];   // 64 rows x 256 cols, +4 pad (banks)
    const int wave = threadIdx.x >> 6;
    const int lane = threadIdx.x & 63;
    const int lrow = lane & 15;   // out-row within tile (D col)
    const int lgrp = lane >> 4;   // out-col quad (D row group)
    const int r0   = blockIdx.x * 64;
    const int rot  = (((blockIdx.x << 3) | wave) * 53) & 127;
    const int cbase = wave * 128;

#define CIDX(j) (cbase + (((j) + rot) & 127))

    // Stationary before^T fragments (B operand), 4 row-tiles, hi/lo.
    short8 bHf[4][2], bLf[4][2];
    #pragma unroll
    for (int rt = 0; rt < 4; ++rt)
        #pragma unroll
        for (int ks = 0; ks < 2; ++ks) {
            const size_t o = (size_t)(r0 + rt * 16 + lrow) * DOUT_K + ks * 32 + lgrp * 8;
            bHf[rt][ks] = *reinterpret_cast<const short8*>(bh + o);
            bLf[rt][ks] = *reinterpret_cast<const short8*>(bl + o);
        }

    float negoff[4];
    #pragma unroll
    for (int rt = 0; rt < 4; ++rt)
        negoff[rt] = -off2[r0 + rt * 16 + lrow];

    float lsum[4] = {0.f, 0.f, 0.f, 0.f};

#define LOADA(H0, H1, c) {                                                  \
    const size_t _b = (size_t)((c) * 2) * 512 + lane * 8;                   \
    H0 = *reinterpret_cast<const short8*>(ahp + _b);                        \
    H1 = *reinterpret_cast<const short8*>(ahp + _b + 512); }

#define LOADB(H0, H1, L0, L1, c) {                                          \
    const size_t _b = (size_t)((c) * 2) * 512 + lane * 8;                   \
    H0 = *reinterpret_cast<const short8*>(ahp + _b);                        \
    H1 = *reinterpret_cast<const short8*>(ahp + _b + 512);                  \
    L0 = *reinterpret_cast<const short8*>(alp + _b);                        \
    L1 = *reinterpret_cast<const short8*>(alp + _b + 512); }

#define BODY1(H0, H1)                                                       \
    _Pragma("unroll")                                                       \
    for (int rt = 0; rt < 4; ++rt) {                                        \
        f32x4 acc = { negoff[rt], negoff[rt], negoff[rt], negoff[rt] };     \
        acc = MFMA16(H0, bHf[rt][0], acc, 0, 0, 0);                         \
        acc = MFMA16(H1, bHf[rt][1], acc, 0, 0, 0);                         \
        acc = MFMA16(H0, bLf[rt][0], acc, 0, 0, 0);                         \
        acc = MFMA16(H1, bLf[rt][1], acc, 0, 0, 0);                         \
        lsum[rt] += (EXP2F(acc[0]) + EXP2F(acc[1]))                         \
                  + (EXP2F(acc[2]) + EXP2F(acc[3])); }

    short8 cH0, cH1, nH0, nH1;

    // ---- pass 1: denominators (2-term, ahp-only, rotated ping-pong) ----
    LOADA(cH0, cH1, CIDX(0));
    for (int j = 0; j < 128; j += 2) {
        LOADA(nH0, nH1, CIDX(j + 1));
        BODY1(cH0, cH1);
        LOADA(cH0, cH1, CIDX(j + 2));
        BODY1(nH0, nH1);
    }

    #pragma unroll
    for (int rt = 0; rt < 4; ++rt) {
        float v = lsum[rt];
        v += __shfl_xor(v, 16, 64);
        v += __shfl_xor(v, 32, 64);
        lsum[rt] = v;
    }
    if (lgrp == 0) {
        #pragma unroll
        for (int rt = 0; rt < 4; ++rt)
            lds[wave][rt * 16 + lrow] = lsum[rt];
    }
    __syncthreads();

    float base2[4];
    #pragma unroll
    for (int rt = 0; rt < 4; ++rt) {
        const int rl = rt * 16 + lrow;
        float tot = ((lds[0][rl] + lds[1][rl]) + (lds[2][rl] + lds[3][rl]))
                  + ((lds[4][rl] + lds[5][rl]) + (lds[6][rl] + lds[7][rl]));
        base2[rt] = negoff[rt] - LOG2F(tot);
    }

    // ---- pass 2: slab-transposed full-page stores ----
    const int rotb = (blockIdx.x * 37) & 63;
    const int k0 = wave * 2, k1 = wave * 2 + 1;

#define LOADPAIR(H00,H01,L00,L01, H10,H11,L10,L11, sp) {                    \
    const int _cc = (sp) * 16 + k0;                                         \
    LOADB(H00, H01, L00, L01, _cc);                                         \
    LOADB(H10, H11, L10, L11, _cc + 1); }

#define BODY2L(H0, H1, L0, L1, kk)                                          \
    _Pragma("unroll")                                                       \
    for (int rt = 0; rt < 4; ++rt) {                                        \
        f32x4 acc = { base2[rt], base2[rt], base2[rt], base2[rt] };         \
        acc = MFMA16(H0, bHf[rt][0], acc, 0, 0, 0);                         \
        acc = MFMA16(H1, bHf[rt][1], acc, 0, 0, 0);                         \
        acc = MFMA16(L0, bHf[rt][0], acc, 0, 0, 0);                         \
        acc = MFMA16(L1, bHf[rt][1], acc, 0, 0, 0);                         \
        acc = MFMA16(H0, bLf[rt][0], acc, 0, 0, 0);                         \
        acc = MFMA16(H1, bLf[rt][1], acc, 0, 0, 0);                         \
        f32x4 o4 = { EXP2F(acc[0]), EXP2F(acc[1]),                          \
                     EXP2F(acc[2]), EXP2F(acc[3]) };                        \
        *reinterpret_cast<f32x4*>(                                          \
            &sout[(rt * 16 + lrow) * 260 + (kk) * 16 + lgrp * 4]) = o4; }

#define STOREPHASE(sp) {                                                    \
    const size_t _cb = (size_t)(sp) * 256;                                  \
    _Pragma("unroll")                                                       \
    for (int i = 0; i < 8; ++i) {                                           \
        const int _rw = wave * 8 + i;                                       \
        const f32x4 v = *reinterpret_cast<const f32x4*>(                    \
            &sout[_rw * 260 + lane * 4]);                                   \
        __builtin_nontemporal_store(v, reinterpret_cast<f32x4*>(            \
            out + (size_t)(r0 + _rw) * M_COLS + _cb + lane * 4)); } }

    short8 A0H0,A0H1,A0L0,A0L1, A1H0,A1H1,A1L0,A1L1;
    short8 B0H0,B0H1,B0L0,B0L1, B1H0,B1H1,B1L0,B1L1;

    LOADPAIR(A0H0,A0H1,A0L0,A0L1, A1H0,A1H1,A1L0,A1L1, rotb);
    for (int s = 0; s < 64; s += 2) {
        const int spE = (s + rotb) & 63;
        const int spO = (s + 1 + rotb) & 63;
        const int spN = (s + 2 + rotb) & 63;   // s=62: wraps to rotb, harmless
        // even slab
        BODY2L(A0H0,A0H1,A0L0,A0L1, k0);
        BODY2L(A1H0,A1H1,A1L0,A1L1, k1);
        LOADPAIR(B0H0,B0H1,B0L0,B0L1, B1H0,B1H1,B1L0,B1L1, spO);
        __syncthreads();
        STOREPHASE(spE);
        __syncthreads();
        // odd slab
        BODY2L(B0H0,B0H1,B0L0,B0L1, k0);
        BODY2L(B1H0,B1H1,B1L0,B1L1, k1);
        LOADPAIR(A0H0,A0H1,A0L0,A0L1, A1H0,A1H1,A1L0,A1L1, spN);
        __syncthreads();
        STOREPHASE(spO);
        __syncthreads();
    }
#undef CIDX
#undef LOADA
#undef LOADB
#undef BODY1
#undef LOADPAIR
#undef BODY2L
#undef STOREPHASE
}

extern "C" void kernel_launch(void* const* d_in, const int* in_sizes, int n_in,
                              void* d_out, int out_size, void* d_ws, size_t ws_size,
                              hipStream_t stream) {
    const float* X = (const float*)d_in[0];   // [16384, 256]
    const float* A = (const float*)d_in[1];   // [64, 16384]
    const float* W = (const float*)d_in[2];   // [256, 64]
    float* out = (float*)d_out;               // [16384, 16384]

    char* wsb = (char*)d_ws;
    float*          off2 = (float*)wsb;                                   // 64 KB
    unsigned short* bh   = (unsigned short*)(wsb + (1u << 16));           // 2 MB
    unsigned short* bl   = (unsigned short*)(wsb + (1u << 16) + (1u << 21));
    unsigned short* ahp  = (unsigned short*)(wsb + (1u << 16) + 2u * (1u << 21));
    unsigned short* alp  = (unsigned short*)(wsb + (1u << 16) + 3u * (1u << 21));

    hipLaunchKernelGGL(k_before, dim3(N_ROWS / 4), dim3(256), 0, stream, X, W, off2, bh, bl);
    hipLaunchKernelGGL(k_pack,   dim3(512),        dim3(256), 0, stream, A, ahp, alp);
    hipLaunchKernelGGL(k_main,   dim3(256),        dim3(512), 0, stream, bh, bl, ahp, alp, off2, out);
}